// Round 16
// baseline (106.385 us; speedup 1.0000x reference)
//
#include <hip/hip_runtime.h>

typedef float f32x4 __attribute__((ext_vector_type(4)));
typedef float f32x16 __attribute__((ext_vector_type(16)));
typedef short s16x8 __attribute__((ext_vector_type(8)));
typedef unsigned short u16;
typedef unsigned char u8;
typedef u16 u16x4v __attribute__((ext_vector_type(4)));
typedef u16 u16x8v __attribute__((ext_vector_type(8)));

#define NB 4
#define NN 2048
#define DI 512
#define DOUTC 512
#define KP 3
#define ROWB 2048   // bytes per concatenated A/B row: 512 bf16 | 512 fp8 | 512 fp8

__device__ __forceinline__ u16 f2b(float f) {
  unsigned u = __builtin_bit_cast(unsigned, f);
  unsigned r = u + 0x7fffu + ((u >> 16) & 1u);
  return (u16)(r >> 16);
}
__device__ __forceinline__ float b2f(u16 h) {
  unsigned u = (unsigned)h << 16;
  return __builtin_bit_cast(float, u);
}
// pack 4 f32 -> 4 fp8 e4m3 (hardware cvt, RNE)
__device__ __forceinline__ unsigned pk4_fp8(float a, float b, float c, float d) {
  int r = __builtin_amdgcn_cvt_pk_fp8_f32(a, b, 0, false);
  r = __builtin_amdgcn_cvt_pk_fp8_f32(c, d, r, true);
  return (unsigned)r;
}

// ---------------- prep (merged): blocks 0-1 -> u,v,bsum ; block 2 -> cc ----
__global__ void prep_all(const float* __restrict__ Wv, const float* __restrict__ aw,
                         const float* __restrict__ bk, const float* __restrict__ bv,
                         const float* __restrict__ ab,
                         float* u, float* v, float* bsum, float* cc) {
  if (blockIdx.x < 2) {
    int c = blockIdx.x * 256 + threadIdx.x;
    float a1 = 0.f, a2 = 0.f;
    const float* row = Wv + (size_t)c * DOUTC;
    for (int d = 0; d < DOUTC; ++d) {
      float w = row[d];
      a1 += w * aw[d];
      a2 += w * aw[DOUTC + d];
    }
    u[c] = a1; v[c] = a2;
    bsum[c] = bk[c] + bk[DOUTC + c] + bk[2 * DOUTC + c];
  } else if (threadIdx.x < 64) {
    int l = threadIdx.x;
    float s = 0.f;
    for (int d = l; d < DOUTC; d += 64) s += bv[d] * (aw[d] + aw[DOUTC + d]);
    for (int o = 32; o; o >>= 1) s += __shfl_down(s, o);
    if (l == 0) cc[0] = s + ab[0];
  }
}

// Wk transpose into BkTB [n=512][ROWB]: z=0 -> bf16 W0^T (bytes 0..1023);
// z=1,2 -> fp8 x64 W{1,2}^T (bytes 1024+/1536+).  grid (8,8,3)
__global__ void transWk_k(const float* __restrict__ in, u8* __restrict__ out) {
  __shared__ u16 tile[64][65];
  int z = blockIdx.z;
  const float* inS = in + (size_t)z * DI * DOUTC;
  int r0 = blockIdx.y * 64, c0 = blockIdx.x * 64;
  int t = threadIdx.x;
#pragma unroll
  for (int p = 0; p < 4; ++p) {
    int g = t + p * 256;
    int r = g >> 4, c4 = (g & 15) << 2;
    f32x4 x = *(const f32x4*)(inS + (size_t)(r0 + r) * DOUTC + c0 + c4);
    tile[r][c4+0] = f2b(x[0]); tile[r][c4+1] = f2b(x[1]);
    tile[r][c4+2] = f2b(x[2]); tile[r][c4+3] = f2b(x[3]);
  }
  __syncthreads();
#pragma unroll
  for (int p = 0; p < 4; ++p) {
    int g = t + p * 256;
    int oc = g >> 4, o4 = (g & 15) << 2;
    if (z == 0) {
      u16x4v wv;
      wv[0] = tile[o4+0][oc]; wv[1] = tile[o4+1][oc];
      wv[2] = tile[o4+2][oc]; wv[3] = tile[o4+3][oc];
      *(u16x4v*)(out + (size_t)(c0 + oc) * ROWB + (size_t)(r0 + o4) * 2) = wv;
    } else {
      unsigned w4 = pk4_fp8(b2f(tile[o4+0][oc]) * 64.f, b2f(tile[o4+1][oc]) * 64.f,
                            b2f(tile[o4+2][oc]) * 64.f, b2f(tile[o4+3][oc]) * 64.f);
      *(unsigned*)(out + (size_t)(c0 + oc) * ROWB + 1024 + (z - 1) * 512 + r0 + o4) = w4;
    }
  }
}

// X transpose (fp8 XbT) + bf16 copy into X123B bytes 0..1023 + fused sj/si dots.
// grid (8, 32, NB)
__global__ void transX_k(const float* __restrict__ X, u8* __restrict__ XbT,
                         u8* __restrict__ X123B,
                         const float* __restrict__ u, const float* __restrict__ v,
                         float* __restrict__ Pj, float* __restrict__ Pi) {
  __shared__ u16 tile[64][65];
  int z = blockIdx.z;
  const float* inS = X + (size_t)z * NN * DI;
  int r0 = blockIdx.y * 64, c0 = blockIdx.x * 64;
  int t = threadIdx.x, cl = t & 15;
  f32x4 u4 = *(const f32x4*)(u + c0 + cl * 4);
  f32x4 v4 = *(const f32x4*)(v + c0 + cl * 4);
#pragma unroll
  for (int p = 0; p < 4; ++p) {
    int g = t + p * 256;
    int r = g >> 4, c4 = cl << 2;
    f32x4 x = *(const f32x4*)(inS + (size_t)(r0 + r) * DI + c0 + c4);
    u16x4v bv4;
    bv4[0] = f2b(x[0]); bv4[1] = f2b(x[1]); bv4[2] = f2b(x[2]); bv4[3] = f2b(x[3]);
    tile[r][c4+0] = bv4[0]; tile[r][c4+1] = bv4[1];
    tile[r][c4+2] = bv4[2]; tile[r][c4+3] = bv4[3];
    *(u16x4v*)(X123B + (size_t)z * NN * ROWB + (size_t)(r0 + r) * ROWB +
               (size_t)(c0 + c4) * 2) = bv4;
    float s1 = x[0]*u4[0] + x[1]*u4[1] + x[2]*u4[2] + x[3]*u4[3];
    float s2 = x[0]*v4[0] + x[1]*v4[1] + x[2]*v4[2] + x[3]*v4[3];
#pragma unroll
    for (int m = 1; m < 16; m <<= 1) {
      s1 += __shfl_xor(s1, m);
      s2 += __shfl_xor(s2, m);
    }
    if (cl == 0) {
      int gr = z * NN + r0 + r;
      Pj[(size_t)blockIdx.x * (NB * NN) + gr] = s1;
      Pi[(size_t)blockIdx.x * (NB * NN) + gr] = s2;
    }
  }
  __syncthreads();
#pragma unroll
  for (int p = 0; p < 4; ++p) {
    int g = t + p * 256;
    int oc = g >> 4, o4 = (g & 15) << 2;
    unsigned w4 = pk4_fp8(b2f(tile[o4+0][oc]), b2f(tile[o4+1][oc]),
                          b2f(tile[o4+2][oc]), b2f(tile[o4+3][oc]));
    *(unsigned*)(XbT + (size_t)z * DI * NN + (size_t)(c0 + oc) * NN + r0 + o4) = w4;
  }
}

// sj[r] = sum_cb Pj[cb][r]  (fixed order -> deterministic)
__global__ void sjsi_red(const float* __restrict__ Pj, const float* __restrict__ Pi,
                         float* __restrict__ sj, float* __restrict__ si) {
  int r = blockIdx.x * 256 + threadIdx.x;
  float s1 = 0.f, s2 = 0.f;
#pragma unroll
  for (int cb = 0; cb < 8; ++cb) {
    s1 += Pj[(size_t)cb * (NB * NN) + r];
    s2 += Pi[(size_t)cb * (NB * NN) + r];
  }
  sj[r] = s1; si[r] = s2;
}

// one wave per row: denom + transition. T stored as fp8 e4m3 scaled x256.
__global__ void tmat_kernel(const float* __restrict__ Aa, const float* __restrict__ sj,
                            const float* __restrict__ si, const float* __restrict__ ccp,
                            u8* __restrict__ T, int rowbase) {
  int wid = threadIdx.x >> 6, lane = threadIdx.x & 63;
  int lr = blockIdx.x * 4 + wid;
  int gi = rowbase + lr;
  int b = gi >> 11;
  float siv = si[gi] + ccp[0];
  const f32x4* Arow = (const f32x4*)(Aa + (size_t)gi * NN);
  const f32x4* sjr = (const f32x4*)(sj + (size_t)b * NN);
  f32x4 al[8];
  float sum = 0.f;
#pragma unroll
  for (int t = 0; t < 8; ++t) {
    int f4 = lane + 64 * t;
    f32x4 a = Arow[f4];
    f32x4 s = sjr[f4];
#pragma unroll
    for (int j = 0; j < 4; ++j) {
      float e = s[j] + siv;
      e = e > 0.f ? e : 0.2f * e;
      al[t][j] = a[j] * __expf(e);
      sum += al[t][j];
    }
  }
#pragma unroll
  for (int o = 1; o < 64; o <<= 1) sum += __shfl_xor(sum, o);
  float rs = 256.0f / (sum + 1e-12f);
  u8* Trow = T + (size_t)lr * NN;
#pragma unroll
  for (int t = 0; t < 8; ++t) {
    int f4 = lane + 64 * t;
    unsigned w4 = pk4_fp8(al[t][0] * rs, al[t][1] * rs, al[t][2] * rs, al[t][3] * rs);
    *(unsigned*)(Trow + 4 * f4) = w4;
  }
}

__device__ __forceinline__ void gload16(const void* g, const void* l) {
  __builtin_amdgcn_global_load_lds((const __attribute__((address_space(1))) void*)g,
                                   (__attribute__((address_space(3))) void*)l, 16, 0, 0);
}

// ---- fp8 T-GEMM (R15 HW-validated): 32x32x16 fp8 MFMA body. ----
struct Gemm8P {
  const u8 *Ab;              // M x K fp8, ldA bytes
  const u8 *Bb;              // N x K fp8, ldB bytes
  u8* outR;                  // row-major fp8 out, ldOB bytes
  u8* outT;                  // optional transposed fp8 out, ldOT bytes
  int ldA, ldB, ldOB, ldOT;
  size_t batchA, batchB, batchOutB, batchOutT;
  float oscR;
};

template <int KT, bool OTR>
__launch_bounds__(256)
__global__ void gemm8_k(Gemm8P p) {
  __shared__ u8 As[3][128 * 128];
  __shared__ u8 Bs[3][64 * 128];
  int tid = threadIdx.x;
  int lane = tid & 63;
  int w = tid >> 6;
  int wr = w >> 1, wc = w & 1;
  int bm = blockIdx.x, bn = blockIdx.y, bz = blockIdx.z;
  int wub = (tid & 192) * 16;
  f32x16 acc2[2] = {};
  const u8* Ag = p.Ab + (size_t)bz * p.batchA + (size_t)bm * 128 * p.ldA;
  const u8* Bg = p.Bb + (size_t)bz * p.batchB + (size_t)bn * 64 * p.ldB;

  auto stage = [&](int t, int buf) {
    int k0 = t * 128;
#pragma unroll
    for (int q = 0; q < 4; ++q) {
      int ch = q * 256 + tid;
      int row = ch >> 3;
      int c8 = (ch & 7) ^ (row & 7);
      gload16(Ag + (size_t)row * p.ldA + k0 + c8 * 16, &As[buf][0] + q * 4096 + wub);
    }
#pragma unroll
    for (int q = 0; q < 2; ++q) {
      int ch = q * 256 + tid;
      int row = ch >> 3;
      int c8 = (ch & 7) ^ (row & 7);
      gload16(Bg + (size_t)row * p.ldB + k0 + c8 * 16, &Bs[buf][0] + q * 4096 + wub);
    }
  };

  constexpr int TOT = KT;
  stage(0, 0);
  stage(1, 1);
  asm volatile("s_waitcnt vmcnt(6)" ::: "memory");
  __builtin_amdgcn_s_barrier();
  __builtin_amdgcn_sched_barrier(0);

  int cl = lane & 31;
  int kb = (lane >> 5) << 3;
  int sw3 = cl & 7;
  size_t ar0 = (size_t)(wr * 64 + cl) * 128;
  size_t ar1 = ar0 + 32 * 128;
  size_t br  = (size_t)(wc * 32 + cl) * 128;

  int bufc = 0;
  for (int t = 0; t < TOT; ++t) {
    int nb = t + 2;
    if (nb < TOT) stage(nb, bufc == 0 ? 2 : bufc - 1);
    const u8* Asb = &As[bufc][0];
    const u8* Bsb = &Bs[bufc][0];
#pragma unroll
    for (int kk = 0; kk < 8; ++kk) {
      int co = ((kk ^ sw3) << 4) + kb;
      long a0 = *(const long*)(Asb + ar0 + co);
      long a1 = *(const long*)(Asb + ar1 + co);
      long b0 = *(const long*)(Bsb + br + co);
      acc2[0] = __builtin_amdgcn_mfma_f32_32x32x16_fp8_fp8(a0, b0, acc2[0], 0, 0, 0);
      acc2[1] = __builtin_amdgcn_mfma_f32_32x32x16_fp8_fp8(a1, b0, acc2[1], 0, 0, 0);
    }
    if (nb < TOT) {
      asm volatile("s_waitcnt vmcnt(6)" ::: "memory");
    } else if (t + 1 < TOT) {
      asm volatile("s_waitcnt vmcnt(0)" ::: "memory");
    }
    if (t + 1 < TOT) {
      __builtin_amdgcn_s_barrier();
      __builtin_amdgcn_sched_barrier(0);
    }
    bufc = bufc + 1; if (bufc == 3) bufc = 0;
  }

  int rb = bm * 128 + wr * 64, cb = bn * 64 + wc * 32;
  int rsh = (lane >> 5) << 2;
  int cidx = cb + cl;
  u8* o = p.outR + (size_t)bz * p.batchOutB;
  u8* oT = OTR ? p.outT + (size_t)bz * p.batchOutT : nullptr;
#pragma unroll
  for (int m = 0; m < 2; ++m)
#pragma unroll
    for (int g = 0; g < 4; ++g) {
      int r0 = rb + m * 32 + g * 8 + rsh;
      unsigned w4 = pk4_fp8(acc2[m][4*g+0] * p.oscR, acc2[m][4*g+1] * p.oscR,
                            acc2[m][4*g+2] * p.oscR, acc2[m][4*g+3] * p.oscR);
#pragma unroll
      for (int r = 0; r < 4; ++r)
        o[(size_t)(r0 + r) * p.ldOB + cidx] = (u8)(w4 >> (8 * r));
      if constexpr (OTR) {
        *(unsigned*)(oT + (size_t)cidx * p.ldOT + r0) = w4;
      }
    }
}

// ---- mixed-precision output GEMM, 32x32 MFMA both phases.
// A,B rows are 2048-byte concat [512 bf16 | 512 fp8 x16*64-scaled pair].
// BK = 128 bytes, TOT = 16: t<8 bf16 32x32x16 -> accB; t>=8 fp8 32x32x16
// -> acc8. Same staged skeleton; both accs share the 32x32 C layout. ----
struct GemmMixP {
  const u8 *Ab;              // [8192 rows][ROWB]
  const u8 *Bb;              // [512 rows][ROWB]
  const float* bias;
  float* out;                // f32 [8192][512]
};

__launch_bounds__(256)
__global__ void gemm_mix_k(GemmMixP p) {
  __shared__ u8 As[3][128 * 128];
  __shared__ u8 Bs[3][64 * 128];
  int tid = threadIdx.x;
  int lane = tid & 63;
  int w = tid >> 6;
  int wr = w >> 1, wc = w & 1;
  int bm = blockIdx.x, bn = blockIdx.y;
  int wub = (tid & 192) * 16;
  f32x16 accB[2] = {};
  f32x16 acc8[2] = {};
  const u8* Ag = p.Ab + (size_t)bm * 128 * ROWB;
  const u8* Bg = p.Bb + (size_t)bn * 64 * ROWB;

  auto stage = [&](int t, int buf) {
    int k0 = t * 128;
#pragma unroll
    for (int q = 0; q < 4; ++q) {
      int ch = q * 256 + tid;
      int row = ch >> 3;
      int c8 = (ch & 7) ^ (row & 7);
      gload16(Ag + (size_t)row * ROWB + k0 + c8 * 16, &As[buf][0] + q * 4096 + wub);
    }
#pragma unroll
    for (int q = 0; q < 2; ++q) {
      int ch = q * 256 + tid;
      int row = ch >> 3;
      int c8 = (ch & 7) ^ (row & 7);
      gload16(Bg + (size_t)row * ROWB + k0 + c8 * 16, &Bs[buf][0] + q * 4096 + wub);
    }
  };

  constexpr int TOT = 16;
  stage(0, 0);
  stage(1, 1);
  asm volatile("s_waitcnt vmcnt(6)" ::: "memory");
  __builtin_amdgcn_s_barrier();
  __builtin_amdgcn_sched_barrier(0);

  int cl = lane & 31;
  int sw3 = cl & 7;
  size_t ar0 = (size_t)(wr * 64 + cl) * 128;
  size_t ar1 = ar0 + 32 * 128;
  size_t br  = (size_t)(wc * 32 + cl) * 128;

  int bufc = 0;
  for (int t = 0; t < TOT; ++t) {
    int nb = t + 2;
    if (nb < TOT) stage(nb, bufc == 0 ? 2 : bufc - 1);
    const u8* Asb = &As[bufc][0];
    const u8* Bsb = &Bs[bufc][0];
    if (t < 8) {
      // bf16 phase: 64 elems (128 B). Per kk: lane reads 16 B (8 bf16) at
      // elem k = kk*16 + (lane>>5)*8 -> chunk c = kk*2 + (lane>>5).
      int kb16 = (lane >> 5) << 4;
#pragma unroll
      for (int kk = 0; kk < 4; ++kk) {
        int c = (kk << 1) + (lane >> 5);
        int co = ((c ^ sw3) << 4);
        (void)kb16;
        s16x8 a0 = *(const s16x8*)(Asb + ar0 + co);
        s16x8 a1 = *(const s16x8*)(Asb + ar1 + co);
        s16x8 b0 = *(const s16x8*)(Bsb + br + co);
        accB[0] = __builtin_amdgcn_mfma_f32_32x32x16_bf16(a0, b0, accB[0], 0, 0, 0);
        accB[1] = __builtin_amdgcn_mfma_f32_32x32x16_bf16(a1, b0, accB[1], 0, 0, 0);
      }
    } else {
      // fp8 phase: 128 elems. Per kk: 8 B at k = kk*16 + (lane>>5)*8.
      int kb = (lane >> 5) << 3;
#pragma unroll
      for (int kk = 0; kk < 8; ++kk) {
        int co = ((kk ^ sw3) << 4) + kb;
        long a0 = *(const long*)(Asb + ar0 + co);
        long a1 = *(const long*)(Asb + ar1 + co);
        long b0 = *(const long*)(Bsb + br + co);
        acc8[0] = __builtin_amdgcn_mfma_f32_32x32x16_fp8_fp8(a0, b0, acc8[0], 0, 0, 0);
        acc8[1] = __builtin_amdgcn_mfma_f32_32x32x16_fp8_fp8(a1, b0, acc8[1], 0, 0, 0);
      }
    }
    if (nb < TOT) {
      asm volatile("s_waitcnt vmcnt(6)" ::: "memory");
    } else if (t + 1 < TOT) {
      asm volatile("s_waitcnt vmcnt(0)" ::: "memory");
    }
    if (t + 1 < TOT) {
      __builtin_amdgcn_s_barrier();
      __builtin_amdgcn_sched_barrier(0);
    }
    bufc = bufc + 1; if (bufc == 3) bufc = 0;
  }

  int rb = bm * 128 + wr * 64, cb = bn * 64 + wc * 32;
  int rsh = (lane >> 5) << 2;
  int cidx = cb + cl;
  float bv_ = p.bias[cidx];
  const float inv = 1.0f / 1024.0f;   // (x16 A) * (x64 B)
#pragma unroll
  for (int m = 0; m < 2; ++m)
#pragma unroll
    for (int g = 0; g < 4; ++g) {
      int r0 = rb + m * 32 + g * 8 + rsh;
#pragma unroll
      for (int r = 0; r < 4; ++r) {
        float val = accB[m][4*g+r] + acc8[m][4*g+r] * inv + bv_;
        p.out[(size_t)(r0 + r) * DOUTC + cidx] = val > 0.f ? val : 0.f;
      }
    }
}

// ---------------- launch ----------------
extern "C" void kernel_launch(void* const* d_in, const int* in_sizes, int n_in,
                              void* d_out, int out_size, void* d_ws, size_t ws_size,
                              hipStream_t stream) {
  const float* X  = (const float*)d_in[0];
  const float* A  = (const float*)d_in[1];
  const float* Wv = (const float*)d_in[2];
  const float* bv = (const float*)d_in[3];
  const float* aw = (const float*)d_in[4];
  const float* ab = (const float*)d_in[5];
  const float* Wk = (const float*)d_in[6];
  const float* bk = (const float*)d_in[7];
  float* out = (float*)d_out;

  char* ws = (char*)d_ws;
  size_t off = 0;
  auto alloc = [&](size_t bytes) -> void* {
    void* p = (void*)(ws + off);
    off = (off + bytes + 255) & ~(size_t)255;
    return p;
  };
  float* u    = (float*)alloc(DI * 4);
  float* v    = (float*)alloc(DI * 4);
  float* cc   = (float*)alloc(256);
  float* bsum = (float*)alloc(DOUTC * 4);
  float* sj   = (float*)alloc((size_t)NB * NN * 4);
  float* si   = (float*)alloc((size_t)NB * NN * 4);
  float* Pj   = (float*)alloc((size_t)8 * NB * NN * 4);
  float* Pi   = (float*)alloc((size_t)8 * NB * NN * 4);
  u8* BkTB  = (u8*)alloc((size_t)DOUTC * ROWB);                // [n][2048 B]
  u8* XbT8  = (u8*)alloc((size_t)NB * DI * NN);                // fp8 X^T
  u8* X123B = (u8*)alloc((size_t)NB * NN * ROWB);              // [b][row][2048 B]
  u8* X1bT8 = (u8*)alloc((size_t)NB * DOUTC * NN);             // fp8 (16*X1)^T
  size_t fixedEnd = off;
  int G = 4;
  while (G > 1 && fixedEnd + (size_t)G * NN * NN > ws_size) G >>= 1;
  u8* Tb8 = (u8*)alloc((size_t)G * NN * NN);                   // fp8 T (x256)

  prep_all<<<3, 256, 0, stream>>>(Wv, aw, bk, bv, ab, u, v, bsum, cc);
  transWk_k<<<dim3(8, 8, 3), 256, 0, stream>>>(Wk, BkTB);
  transX_k<<<dim3(8, 32, NB), 256, 0, stream>>>(X, XbT8, X123B, u, v, Pj, Pi);
  sjsi_red<<<NB * NN / 256, 256, 0, stream>>>(Pj, Pi, sj, si);

  for (int g0 = 0; g0 < NB; g0 += G) {
    tmat_kernel<<<G * NN / 4, 256, 0, stream>>>(A, sj, si, cc, Tb8, g0 * NN);

    // X1 = T @ X : acc = 256*X1. Row fp8 (16*X1) into X123B bytes 1024..1535;
    // transposed fp8 (16*X1) for gemm2's B.
    Gemm8P p1{};
    p1.Ab = Tb8;
    p1.Bb = XbT8 + (size_t)g0 * DI * NN;
    p1.outR = X123B + (size_t)g0 * NN * ROWB + 1024;
    p1.outT = X1bT8 + (size_t)g0 * DOUTC * NN;
    p1.ldA = NN; p1.ldB = NN; p1.ldOB = ROWB; p1.ldOT = NN;
    p1.batchA = (size_t)NN * NN; p1.batchB = (size_t)DI * NN;
    p1.batchOutB = (size_t)NN * ROWB; p1.batchOutT = (size_t)DOUTC * NN;
    p1.oscR = 16.0f / 256.0f;
    gemm8_k<16, true><<<dim3(16, 8, G), 256, 0, stream>>>(p1);

    // X2 = T @ X1 : acc = 256*16*X2 = 4096*X2. Row fp8 (16*X2) into bytes 1536+.
    Gemm8P p2 = p1;
    p2.Bb = X1bT8 + (size_t)g0 * DOUTC * NN;
    p2.outR = X123B + (size_t)g0 * NN * ROWB + 1536;
    p2.outT = nullptr;
    p2.oscR = 16.0f / 4096.0f;
    gemm8_k<16, false><<<dim3(16, 8, G), 256, 0, stream>>>(p2);
  }

  // H = relu( X@W0 (bf16) + (X1@W1 + X2@W2) (fp8) + bsum )
  GemmMixP p3{};
  p3.Ab = X123B; p3.Bb = BkTB; p3.bias = bsum; p3.out = out;
  gemm_mix_k<<<dim3(64, 8, 1), 256, 0, stream>>>(p3);
}

// Round 17
// 105.804 us; speedup vs baseline: 1.0055x; 1.0055x over previous
//
#include <hip/hip_runtime.h>

typedef float f32x4 __attribute__((ext_vector_type(4)));
typedef float f32x16 __attribute__((ext_vector_type(16)));
typedef short s16x8 __attribute__((ext_vector_type(8)));
typedef unsigned short u16;
typedef unsigned char u8;
typedef u16 u16x4v __attribute__((ext_vector_type(4)));
typedef u16 u16x8v __attribute__((ext_vector_type(8)));

#define NB 4
#define NN 2048
#define DI 512
#define DOUTC 512
#define KP 3
#define ROWB 2048   // bytes per concatenated A/B row: 512 bf16 | 512 fp8 | 512 fp8

__device__ __forceinline__ u16 f2b(float f) {
  unsigned u = __builtin_bit_cast(unsigned, f);
  unsigned r = u + 0x7fffu + ((u >> 16) & 1u);
  return (u16)(r >> 16);
}
__device__ __forceinline__ float b2f(u16 h) {
  unsigned u = (unsigned)h << 16;
  return __builtin_bit_cast(float, u);
}
// pack 4 f32 -> 4 fp8 e4m3 (hardware cvt, RNE)
__device__ __forceinline__ unsigned pk4_fp8(float a, float b, float c, float d) {
  int r = __builtin_amdgcn_cvt_pk_fp8_f32(a, b, 0, false);
  r = __builtin_amdgcn_cvt_pk_fp8_f32(c, d, r, true);
  return (unsigned)r;
}

// ---------------- prep (merged): blocks 0-1 -> u,v,bsum ; block 2 -> cc ----
__global__ void prep_all(const float* __restrict__ Wv, const float* __restrict__ aw,
                         const float* __restrict__ bk, const float* __restrict__ bv,
                         const float* __restrict__ ab,
                         float* u, float* v, float* bsum, float* cc) {
  if (blockIdx.x < 2) {
    int c = blockIdx.x * 256 + threadIdx.x;
    float a1 = 0.f, a2 = 0.f;
    const float* row = Wv + (size_t)c * DOUTC;
    for (int d = 0; d < DOUTC; ++d) {
      float w = row[d];
      a1 += w * aw[d];
      a2 += w * aw[DOUTC + d];
    }
    u[c] = a1; v[c] = a2;
    bsum[c] = bk[c] + bk[DOUTC + c] + bk[2 * DOUTC + c];
  } else if (threadIdx.x < 64) {
    int l = threadIdx.x;
    float s = 0.f;
    for (int d = l; d < DOUTC; d += 64) s += bv[d] * (aw[d] + aw[DOUTC + d]);
    for (int o = 32; o; o >>= 1) s += __shfl_down(s, o);
    if (l == 0) cc[0] = s + ab[0];
  }
}

// Wk transpose into BkTB [n=512][ROWB]: z=0 -> bf16 W0^T (bytes 0..1023);
// z=1,2 -> fp8 x64 W{1,2}^T (bytes 1024+/1536+).  grid (8,8,3)
__global__ void transWk_k(const float* __restrict__ in, u8* __restrict__ out) {
  __shared__ u16 tile[64][65];
  int z = blockIdx.z;
  const float* inS = in + (size_t)z * DI * DOUTC;
  int r0 = blockIdx.y * 64, c0 = blockIdx.x * 64;
  int t = threadIdx.x;
#pragma unroll
  for (int p = 0; p < 4; ++p) {
    int g = t + p * 256;
    int r = g >> 4, c4 = (g & 15) << 2;
    f32x4 x = *(const f32x4*)(inS + (size_t)(r0 + r) * DOUTC + c0 + c4);
    tile[r][c4+0] = f2b(x[0]); tile[r][c4+1] = f2b(x[1]);
    tile[r][c4+2] = f2b(x[2]); tile[r][c4+3] = f2b(x[3]);
  }
  __syncthreads();
#pragma unroll
  for (int p = 0; p < 4; ++p) {
    int g = t + p * 256;
    int oc = g >> 4, o4 = (g & 15) << 2;
    if (z == 0) {
      u16x4v wv;
      wv[0] = tile[o4+0][oc]; wv[1] = tile[o4+1][oc];
      wv[2] = tile[o4+2][oc]; wv[3] = tile[o4+3][oc];
      *(u16x4v*)(out + (size_t)(c0 + oc) * ROWB + (size_t)(r0 + o4) * 2) = wv;
    } else {
      unsigned w4 = pk4_fp8(b2f(tile[o4+0][oc]) * 64.f, b2f(tile[o4+1][oc]) * 64.f,
                            b2f(tile[o4+2][oc]) * 64.f, b2f(tile[o4+3][oc]) * 64.f);
      *(unsigned*)(out + (size_t)(c0 + oc) * ROWB + 1024 + (z - 1) * 512 + r0 + o4) = w4;
    }
  }
}

// X transpose (fp8 XbT) + bf16 copy into X123B bytes 0..1023 + fused sj/si dots.
// grid (8, 32, NB)
__global__ void transX_k(const float* __restrict__ X, u8* __restrict__ XbT,
                         u8* __restrict__ X123B,
                         const float* __restrict__ u, const float* __restrict__ v,
                         float* __restrict__ Pj, float* __restrict__ Pi) {
  __shared__ u16 tile[64][65];
  int z = blockIdx.z;
  const float* inS = X + (size_t)z * NN * DI;
  int r0 = blockIdx.y * 64, c0 = blockIdx.x * 64;
  int t = threadIdx.x, cl = t & 15;
  f32x4 u4 = *(const f32x4*)(u + c0 + cl * 4);
  f32x4 v4 = *(const f32x4*)(v + c0 + cl * 4);
#pragma unroll
  for (int p = 0; p < 4; ++p) {
    int g = t + p * 256;
    int r = g >> 4, c4 = cl << 2;
    f32x4 x = *(const f32x4*)(inS + (size_t)(r0 + r) * DI + c0 + c4);
    u16x4v bv4;
    bv4[0] = f2b(x[0]); bv4[1] = f2b(x[1]); bv4[2] = f2b(x[2]); bv4[3] = f2b(x[3]);
    tile[r][c4+0] = bv4[0]; tile[r][c4+1] = bv4[1];
    tile[r][c4+2] = bv4[2]; tile[r][c4+3] = bv4[3];
    *(u16x4v*)(X123B + (size_t)z * NN * ROWB + (size_t)(r0 + r) * ROWB +
               (size_t)(c0 + c4) * 2) = bv4;
    float s1 = x[0]*u4[0] + x[1]*u4[1] + x[2]*u4[2] + x[3]*u4[3];
    float s2 = x[0]*v4[0] + x[1]*v4[1] + x[2]*v4[2] + x[3]*v4[3];
#pragma unroll
    for (int m = 1; m < 16; m <<= 1) {
      s1 += __shfl_xor(s1, m);
      s2 += __shfl_xor(s2, m);
    }
    if (cl == 0) {
      int gr = z * NN + r0 + r;
      Pj[(size_t)blockIdx.x * (NB * NN) + gr] = s1;
      Pi[(size_t)blockIdx.x * (NB * NN) + gr] = s2;
    }
  }
  __syncthreads();
#pragma unroll
  for (int p = 0; p < 4; ++p) {
    int g = t + p * 256;
    int oc = g >> 4, o4 = (g & 15) << 2;
    unsigned w4 = pk4_fp8(b2f(tile[o4+0][oc]), b2f(tile[o4+1][oc]),
                          b2f(tile[o4+2][oc]), b2f(tile[o4+3][oc]));
    *(unsigned*)(XbT + (size_t)z * DI * NN + (size_t)(c0 + oc) * NN + r0 + o4) = w4;
  }
}

// sj[r] = sum_cb Pj[cb][r]  (fixed order -> deterministic)
__global__ void sjsi_red(const float* __restrict__ Pj, const float* __restrict__ Pi,
                         float* __restrict__ sj, float* __restrict__ si) {
  int r = blockIdx.x * 256 + threadIdx.x;
  float s1 = 0.f, s2 = 0.f;
#pragma unroll
  for (int cb = 0; cb < 8; ++cb) {
    s1 += Pj[(size_t)cb * (NB * NN) + r];
    s2 += Pi[(size_t)cb * (NB * NN) + r];
  }
  sj[r] = s1; si[r] = s2;
}

// one wave per row: denom + transition. T stored as fp8 e4m3 scaled x256.
__global__ void tmat_kernel(const float* __restrict__ Aa, const float* __restrict__ sj,
                            const float* __restrict__ si, const float* __restrict__ ccp,
                            u8* __restrict__ T, int rowbase) {
  int wid = threadIdx.x >> 6, lane = threadIdx.x & 63;
  int lr = blockIdx.x * 4 + wid;
  int gi = rowbase + lr;
  int b = gi >> 11;
  float siv = si[gi] + ccp[0];
  const f32x4* Arow = (const f32x4*)(Aa + (size_t)gi * NN);
  const f32x4* sjr = (const f32x4*)(sj + (size_t)b * NN);
  f32x4 al[8];
  float sum = 0.f;
#pragma unroll
  for (int t = 0; t < 8; ++t) {
    int f4 = lane + 64 * t;
    f32x4 a = Arow[f4];
    f32x4 s = sjr[f4];
#pragma unroll
    for (int j = 0; j < 4; ++j) {
      float e = s[j] + siv;
      e = e > 0.f ? e : 0.2f * e;
      al[t][j] = a[j] * __expf(e);
      sum += al[t][j];
    }
  }
#pragma unroll
  for (int o = 1; o < 64; o <<= 1) sum += __shfl_xor(sum, o);
  float rs = 256.0f / (sum + 1e-12f);
  u8* Trow = T + (size_t)lr * NN;
#pragma unroll
  for (int t = 0; t < 8; ++t) {
    int f4 = lane + 64 * t;
    unsigned w4 = pk4_fp8(al[t][0] * rs, al[t][1] * rs, al[t][2] * rs, al[t][3] * rs);
    *(unsigned*)(Trow + 4 * f4) = w4;
  }
}

__device__ __forceinline__ void gload16(const void* g, const void* l) {
  __builtin_amdgcn_global_load_lds((const __attribute__((address_space(1))) void*)g,
                                   (__attribute__((address_space(3))) void*)l, 16, 0, 0);
}

// ---- fp8 T-GEMM: R13/R14 HW-validated staging/sync skeleton; compute body
// v_mfma_f32_32x32x16_fp8_fp8 (R15 HW-validated). C layout (m74/m101):
// col=lane&31, row=(reg&3)+8*(reg>>2)+4*(lane>>5). ----
struct Gemm8P {
  const u8 *Ab;              // M x K fp8, ldA bytes
  const u8 *Bb;              // N x K fp8, ldB bytes
  u8* outR;                  // row-major fp8 out, ldOB bytes
  u8* outT;                  // optional transposed fp8 out, ldOT bytes
  int ldA, ldB, ldOB, ldOT;
  size_t batchA, batchB, batchOutB, batchOutT;
  float oscR;
};

template <int KT, bool OTR>
__launch_bounds__(256)
__global__ void gemm8_k(Gemm8P p) {
  __shared__ u8 As[3][128 * 128];
  __shared__ u8 Bs[3][64 * 128];
  int tid = threadIdx.x;
  int lane = tid & 63;
  int w = tid >> 6;
  int wr = w >> 1, wc = w & 1;
  int bm = blockIdx.x, bn = blockIdx.y, bz = blockIdx.z;
  int wub = (tid & 192) * 16;
  f32x16 acc2[2] = {};
  const u8* Ag = p.Ab + (size_t)bz * p.batchA + (size_t)bm * 128 * p.ldA;
  const u8* Bg = p.Bb + (size_t)bz * p.batchB + (size_t)bn * 64 * p.ldB;

  auto stage = [&](int t, int buf) {
    int k0 = t * 128;
#pragma unroll
    for (int q = 0; q < 4; ++q) {
      int ch = q * 256 + tid;
      int row = ch >> 3;
      int c8 = (ch & 7) ^ (row & 7);
      gload16(Ag + (size_t)row * p.ldA + k0 + c8 * 16, &As[buf][0] + q * 4096 + wub);
    }
#pragma unroll
    for (int q = 0; q < 2; ++q) {
      int ch = q * 256 + tid;
      int row = ch >> 3;
      int c8 = (ch & 7) ^ (row & 7);
      gload16(Bg + (size_t)row * p.ldB + k0 + c8 * 16, &Bs[buf][0] + q * 4096 + wub);
    }
  };

  constexpr int TOT = KT;
  stage(0, 0);
  stage(1, 1);
  asm volatile("s_waitcnt vmcnt(6)" ::: "memory");
  __builtin_amdgcn_s_barrier();
  __builtin_amdgcn_sched_barrier(0);

  // fragment addressing (32x32x16): row = lane&31 (+32 for m=1), 8 bytes at
  // k-chunk kk, intra-chunk offset (lane>>5)*8; swizzle slot = kk ^ (row&7).
  int cl = lane & 31;
  int kb = (lane >> 5) << 3;
  int sw3 = cl & 7;                       // (row&7) identical for ar0/ar1/br
  size_t ar0 = (size_t)(wr * 64 + cl) * 128;
  size_t ar1 = ar0 + 32 * 128;
  size_t br  = (size_t)(wc * 32 + cl) * 128;

  int bufc = 0;
  for (int t = 0; t < TOT; ++t) {
    int nb = t + 2;
    if (nb < TOT) stage(nb, bufc == 0 ? 2 : bufc - 1);
    const u8* Asb = &As[bufc][0];
    const u8* Bsb = &Bs[bufc][0];
#pragma unroll
    for (int kk = 0; kk < 8; ++kk) {
      int co = ((kk ^ sw3) << 4) + kb;
      long a0 = *(const long*)(Asb + ar0 + co);
      long a1 = *(const long*)(Asb + ar1 + co);
      long b0 = *(const long*)(Bsb + br + co);
      acc2[0] = __builtin_amdgcn_mfma_f32_32x32x16_fp8_fp8(a0, b0, acc2[0], 0, 0, 0);
      acc2[1] = __builtin_amdgcn_mfma_f32_32x32x16_fp8_fp8(a1, b0, acc2[1], 0, 0, 0);
    }
    if (nb < TOT) {
      asm volatile("s_waitcnt vmcnt(6)" ::: "memory");
    } else if (t + 1 < TOT) {
      asm volatile("s_waitcnt vmcnt(0)" ::: "memory");
    }
    if (t + 1 < TOT) {
      __builtin_amdgcn_s_barrier();
      __builtin_amdgcn_sched_barrier(0);
    }
    bufc = bufc + 1; if (bufc == 3) bufc = 0;
  }

  int rb = bm * 128 + wr * 64, cb = bn * 64 + wc * 32;
  int rsh = (lane >> 5) << 2;
  int cidx = cb + cl;
  u8* o = p.outR + (size_t)bz * p.batchOutB;
  u8* oT = OTR ? p.outT + (size_t)bz * p.batchOutT : nullptr;
#pragma unroll
  for (int m = 0; m < 2; ++m)
#pragma unroll
    for (int g = 0; g < 4; ++g) {
      int r0 = rb + m * 32 + g * 8 + rsh;
      unsigned w4 = pk4_fp8(acc2[m][4*g+0] * p.oscR, acc2[m][4*g+1] * p.oscR,
                            acc2[m][4*g+2] * p.oscR, acc2[m][4*g+3] * p.oscR);
#pragma unroll
      for (int r = 0; r < 4; ++r)
        o[(size_t)(r0 + r) * p.ldOB + cidx] = (u8)(w4 >> (8 * r));
      if constexpr (OTR) {
        *(unsigned*)(oT + (size_t)cidx * p.ldOT + r0) = w4;
      }
    }
}

// ---- mixed-precision output GEMM: A,B rows are 2048-byte concat
// [512 bf16 | 512 fp8 x16*64-scaled pair]. BK = 128 bytes, TOT = 16:
// t<8 bf16 MFMA -> accB; t>=8 fp8 MFMA -> acc8. Same staged skeleton.
// (R14 HW-validated body — measured fastest vs the 32x32 variant.) ----
struct GemmMixP {
  const u8 *Ab;              // [8192 rows][ROWB]
  const u8 *Bb;              // [512 rows][ROWB]
  const float* bias;
  float* out;                // f32 [8192][512]
};

__launch_bounds__(256)
__global__ void gemm_mix_k(GemmMixP p) {
  __shared__ u8 As[3][128 * 128];
  __shared__ u8 Bs[3][64 * 128];
  int tid = threadIdx.x;
  int lane = tid & 63;
  int w = tid >> 6;
  int wr = w >> 1, wc = w & 1;
  int bm = blockIdx.x, bn = blockIdx.y;
  int rof = lane & 15, ksel = lane >> 4, sw = lane & 7;
  int wub = (tid & 192) * 16;
  f32x4 accB[4][2] = {};
  f32x4 acc8[4][2] = {};
  const u8* Ag = p.Ab + (size_t)bm * 128 * ROWB;
  const u8* Bg = p.Bb + (size_t)bn * 64 * ROWB;

  auto stage = [&](int t, int buf) {
    int k0 = t * 128;
#pragma unroll
    for (int q = 0; q < 4; ++q) {
      int ch = q * 256 + tid;
      int row = ch >> 3;
      int c8 = (ch & 7) ^ (row & 7);
      gload16(Ag + (size_t)row * ROWB + k0 + c8 * 16, &As[buf][0] + q * 4096 + wub);
    }
#pragma unroll
    for (int q = 0; q < 2; ++q) {
      int ch = q * 256 + tid;
      int row = ch >> 3;
      int c8 = (ch & 7) ^ (row & 7);
      gload16(Bg + (size_t)row * ROWB + k0 + c8 * 16, &Bs[buf][0] + q * 4096 + wub);
    }
  };

  constexpr int TOT = 16;
  stage(0, 0);
  stage(1, 1);
  asm volatile("s_waitcnt vmcnt(6)" ::: "memory");
  __builtin_amdgcn_s_barrier();
  __builtin_amdgcn_sched_barrier(0);

  int bufc = 0;
  for (int t = 0; t < TOT; ++t) {
    int nb = t + 2;
    if (nb < TOT) stage(nb, bufc == 0 ? 2 : bufc - 1);
    const u8* Asb = &As[bufc][0];
    const u8* Bsb = &Bs[bufc][0];
    if (t < 8) {
      // bf16 phase: 64 elems (128 B) per iter, 8 chunks of 16 B
#pragma unroll
      for (int kk = 0; kk < 2; ++kk) {
        int csw = ((kk * 4 + ksel) ^ sw) * 16;
        s16x8 af[4], bfr[2];
#pragma unroll
        for (int mf = 0; mf < 4; ++mf) {
          int r = wr * 64 + mf * 16 + rof;
          af[mf] = *(const s16x8*)(Asb + (size_t)r * 128 + csw);
        }
#pragma unroll
        for (int nf = 0; nf < 2; ++nf) {
          int r = wc * 32 + nf * 16 + rof;
          bfr[nf] = *(const s16x8*)(Bsb + (size_t)r * 128 + csw);
        }
#pragma unroll
        for (int mf = 0; mf < 4; ++mf)
#pragma unroll
          for (int nf = 0; nf < 2; ++nf)
            accB[mf][nf] = __builtin_amdgcn_mfma_f32_16x16x32_bf16(af[mf], bfr[nf], accB[mf][nf], 0, 0, 0);
      }
    } else {
      // fp8 phase: 128 elems per iter
#pragma unroll
      for (int kk = 0; kk < 4; ++kk) {
        int csw = ((2 * kk + (ksel >> 1)) ^ sw) * 16 + (ksel & 1) * 8;
        long af[4], bfr[2];
#pragma unroll
        for (int mf = 0; mf < 4; ++mf) {
          int r = wr * 64 + mf * 16 + rof;
          af[mf] = *(const long*)(Asb + (size_t)r * 128 + csw);
        }
#pragma unroll
        for (int nf = 0; nf < 2; ++nf) {
          int r = wc * 32 + nf * 16 + rof;
          bfr[nf] = *(const long*)(Bsb + (size_t)r * 128 + csw);
        }
#pragma unroll
        for (int mf = 0; mf < 4; ++mf)
#pragma unroll
          for (int nf = 0; nf < 2; ++nf)
            acc8[mf][nf] = __builtin_amdgcn_mfma_f32_16x16x32_fp8_fp8(af[mf], bfr[nf], acc8[mf][nf], 0, 0, 0);
      }
    }
    if (nb < TOT) {
      asm volatile("s_waitcnt vmcnt(6)" ::: "memory");
    } else if (t + 1 < TOT) {
      asm volatile("s_waitcnt vmcnt(0)" ::: "memory");
    }
    if (t + 1 < TOT) {
      __builtin_amdgcn_s_barrier();
      __builtin_amdgcn_sched_barrier(0);
    }
    bufc = bufc + 1; if (bufc == 3) bufc = 0;
  }

  int rb = bm * 128 + wr * 64, cb = bn * 64 + wc * 32;
  int rsub = ksel << 2, csub = rof;
  const float inv = 1.0f / 1024.0f;   // (x16 A) * (x64 B)
#pragma unroll
  for (int nf = 0; nf < 2; ++nf) {
    int cidx = cb + nf * 16 + csub;
    float bv_ = p.bias[cidx];
#pragma unroll
    for (int mf = 0; mf < 4; ++mf)
#pragma unroll
      for (int r = 0; r < 4; ++r) {
        float val = accB[mf][nf][r] + acc8[mf][nf][r] * inv + bv_;
        p.out[(size_t)(rb + mf * 16 + rsub + r) * DOUTC + cidx] = val > 0.f ? val : 0.f;
      }
  }
}

// ---------------- launch ----------------
extern "C" void kernel_launch(void* const* d_in, const int* in_sizes, int n_in,
                              void* d_out, int out_size, void* d_ws, size_t ws_size,
                              hipStream_t stream) {
  const float* X  = (const float*)d_in[0];
  const float* A  = (const float*)d_in[1];
  const float* Wv = (const float*)d_in[2];
  const float* bv = (const float*)d_in[3];
  const float* aw = (const float*)d_in[4];
  const float* ab = (const float*)d_in[5];
  const float* Wk = (const float*)d_in[6];
  const float* bk = (const float*)d_in[7];
  float* out = (float*)d_out;

  char* ws = (char*)d_ws;
  size_t off = 0;
  auto alloc = [&](size_t bytes) -> void* {
    void* p = (void*)(ws + off);
    off = (off + bytes + 255) & ~(size_t)255;
    return p;
  };
  float* u    = (float*)alloc(DI * 4);
  float* v    = (float*)alloc(DI * 4);
  float* cc   = (float*)alloc(256);
  float* bsum = (float*)alloc(DOUTC * 4);
  float* sj   = (float*)alloc((size_t)NB * NN * 4);
  float* si   = (float*)alloc((size_t)NB * NN * 4);
  float* Pj   = (float*)alloc((size_t)8 * NB * NN * 4);
  float* Pi   = (float*)alloc((size_t)8 * NB * NN * 4);
  u8* BkTB  = (u8*)alloc((size_t)DOUTC * ROWB);                // [n][2048 B]
  u8* XbT8  = (u8*)alloc((size_t)NB * DI * NN);                // fp8 X^T
  u8* X123B = (u8*)alloc((size_t)NB * NN * ROWB);              // [b][row][2048 B]
  u8* X1bT8 = (u8*)alloc((size_t)NB * DOUTC * NN);             // fp8 (16*X1)^T
  size_t fixedEnd = off;
  int G = 4;
  while (G > 1 && fixedEnd + (size_t)G * NN * NN > ws_size) G >>= 1;
  u8* Tb8 = (u8*)alloc((size_t)G * NN * NN);                   // fp8 T (x256)

  prep_all<<<3, 256, 0, stream>>>(Wv, aw, bk, bv, ab, u, v, bsum, cc);
  transWk_k<<<dim3(8, 8, 3), 256, 0, stream>>>(Wk, BkTB);
  transX_k<<<dim3(8, 32, NB), 256, 0, stream>>>(X, XbT8, X123B, u, v, Pj, Pi);
  sjsi_red<<<NB * NN / 256, 256, 0, stream>>>(Pj, Pi, sj, si);

  for (int g0 = 0; g0 < NB; g0 += G) {
    tmat_kernel<<<G * NN / 4, 256, 0, stream>>>(A, sj, si, cc, Tb8, g0 * NN);

    // X1 = T @ X : acc = 256*X1. Row fp8 (16*X1) into X123B bytes 1024..1535;
    // transposed fp8 (16*X1) for gemm2's B.
    Gemm8P p1{};
    p1.Ab = Tb8;
    p1.Bb = XbT8 + (size_t)g0 * DI * NN;
    p1.outR = X123B + (size_t)g0 * NN * ROWB + 1024;
    p1.outT = X1bT8 + (size_t)g0 * DOUTC * NN;
    p1.ldA = NN; p1.ldB = NN; p1.ldOB = ROWB; p1.ldOT = NN;
    p1.batchA = (size_t)NN * NN; p1.batchB = (size_t)DI * NN;
    p1.batchOutB = (size_t)NN * ROWB; p1.batchOutT = (size_t)DOUTC * NN;
    p1.oscR = 16.0f / 256.0f;
    gemm8_k<16, true><<<dim3(16, 8, G), 256, 0, stream>>>(p1);

    // X2 = T @ X1 : acc = 256*16*X2 = 4096*X2. Row fp8 (16*X2) into bytes 1536+.
    Gemm8P p2 = p1;
    p2.Bb = X1bT8 + (size_t)g0 * DOUTC * NN;
    p2.outR = X123B + (size_t)g0 * NN * ROWB + 1536;
    p2.outT = nullptr;
    p2.oscR = 16.0f / 4096.0f;
    gemm8_k<16, false><<<dim3(16, 8, G), 256, 0, stream>>>(p2);
  }

  // H = relu( X@W0 (bf16) + (X1@W1 + X2@W2) (fp8) + bsum )
  GemmMixP p3{};
  p3.Ab = X123B; p3.Bb = BkTB; p3.bias = bsum; p3.out = out;
  gemm_mix_k<<<dim3(64, 8, 1), 256, 0, stream>>>(p3);
}